// Round 5
// baseline (1071.557 us; speedup 1.0000x reference)
//
#include <hip/hip_runtime.h>
#include <math.h>

#define BATCH 256
#define SEQ 512
#define SDS 54            // floats per (b,t) record: dt[6] hc[6] hs[6] Cc[18] term[18]
#define PI_F 3.14159265358979323846f
#define INV2PI_F 0.15915494309189535f
#define K_HALF_INV2PI 0.07957747154594767f   // 0.5/(2*pi)
#define FOURPI_F 12.566370614359172f

// ---- cross-lane helpers -----------------------------------------------------
template<int CTRL>
__device__ __forceinline__ float fdpp(float v) {
    return __int_as_float(__builtin_amdgcn_mov_dpp(__float_as_int(v), CTRL, 0xF, 0xF, true));
}
template<int L>
__device__ __forceinline__ float rdl(float v) {
    return __int_as_float(__builtin_amdgcn_readlane(__float_as_int(v), L));
}
template<int M>
__device__ __forceinline__ float swz(float v) {   // xor within 32-lane group
    return __int_as_float(__builtin_amdgcn_ds_swizzle(__float_as_int(v), (M << 10) | 0x1F));
}
// sum with xor-16 / xor-32 partner, direction-proof: r[0]+r[1] == v[l]+v[l^m]
// in either swap convention of v_permlane*_swap_b32.
#if __has_builtin(__builtin_amdgcn_permlane16_swap)
__device__ __forceinline__ float sum16(float v) {
    typedef unsigned int u2v __attribute__((ext_vector_type(2)));
    u2v r = __builtin_amdgcn_permlane16_swap(__float_as_uint(v), __float_as_uint(v), false, false);
    return __uint_as_float(r[0]) + __uint_as_float(r[1]);
}
#else
__device__ __forceinline__ float sum16(float v) { return v + swz<16>(v); }
#endif
#if __has_builtin(__builtin_amdgcn_permlane32_swap)
__device__ __forceinline__ float sum32(float v) {
    typedef unsigned int u2v __attribute__((ext_vector_type(2)));
    u2v r = __builtin_amdgcn_permlane32_swap(__float_as_uint(v), __float_as_uint(v), false, false);
    return __uint_as_float(r[0]) + __uint_as_float(r[1]);
}
#else
__device__ __forceinline__ float sum32(float v) { return v + __shfl_xor(v, 32, 64); }
#endif
// generic xor-M lane exchange, VALU/DPP/swizzle only (no bpermute, no barrier)
template<int M>
__device__ __forceinline__ float exg(float v) {
    if constexpr (M == 1)       return fdpp<0xB1>(v);           // quad_perm 1032
    else if constexpr (M == 2)  return fdpp<0x4E>(v);           // quad_perm 2301
    else if constexpr (M == 3)  return fdpp<0x1B>(v);           // quad_perm 3210
    else if constexpr (M == 4)  return fdpp<0x141>(fdpp<0x1B>(v)); // xor7∘xor3
    else if constexpr (M == 8)  return fdpp<0x128>(v);          // row_ror8 ≡ xor8
    else if constexpr (M == 32) return sum32(v) - v;
    else if constexpr (M == 48) { float w = swz<16>(v); return sum32(w) - w; }
    else if constexpr (M == 33) { float w = fdpp<0xB1>(v); return sum32(w) - w; }
    else                        return swz<M>(v);               // 6,12,16,24
}
// full 64-lane sum, uniform in every lane, fully VALU
__device__ __forceinline__ float redsum64(float v) {
    v += fdpp<0x128>(v);
    v += fdpp<0x124>(v);
    v += fdpp<0x122>(v);
    v += fdpp<0x121>(v);           // every lane: its row16 sum
    v = sum16(v);                  // + partner row
    v = sum32(v);                  // + other half
    return v;
}
__device__ __forceinline__ float xorf(float v, int m) {
    return __int_as_float(__float_as_int(v) ^ m);
}
// QSVT per-degree CNOT-block permutation (GF(2)-linear) — verified R1-R6
__device__ __forceinline__ int permf(int x) {
    const int cs[11] = {0,1,2,3,4,5,5,4,3,2,1};
    const int ts[11] = {1,2,3,4,5,0,4,3,2,1,0};
#pragma unroll
    for (int k = 10; k >= 0; k--) {
        int cb = (x >> (5 - cs[k])) & 1;
        x ^= cb << (5 - ts[k]);
    }
    return x;
}
__device__ __forceinline__ void cmul4(const float* c,
    float vr, float vi, float ar, float ai, float br, float bi, float cr, float ci,
    float& nr, float& ni) {
    nr = c[0]*vr - c[1]*vi + c[2]*ar - c[3]*ai + c[4]*br - c[5]*bi + c[6]*cr - c[7]*ci;
    ni = c[0]*vi + c[1]*vr + c[2]*ai + c[3]*ar + c[4]*bi + c[5]*br + c[6]*ci + c[7]*cr;
}
__device__ __forceinline__ void ringapply(const float* rc,
    float vr, float vi, float br, float bi, float cr, float ci, float dr, float di,
    float& nr, float& ni) {
    nr = rc[0]*vr - rc[1]*bi - rc[2]*ci + rc[3]*dr;
    ni = rc[0]*vi + rc[1]*br + rc[2]*cr + rc[3]*di;
}
// gate-stage appliers (linear maps; identical math to umat_kernel — R2-verified
// chain — so applying them to an arbitrary state vector computes U·psi)
template<int MI, int MJ>
__device__ __forceinline__ void p1qS(float& re, float& im, const float* c) {
    float ar = exg<MI>(re),      ai = exg<MI>(im);
    float br = exg<MJ>(re),      bi = exg<MJ>(im);
    float cr = exg<MI | MJ>(re), ci = exg<MI | MJ>(im);
    float nr, ni;
    cmul4(c, re, im, ar, ai, br, bi, cr, ci, nr, ni);
    re = nr; im = ni;
}
template<int MB, int MC>
__device__ __forceinline__ void rngS(float& re, float& im, const float* c) {
    float br = exg<MB>(re),      bi = exg<MB>(im);
    float cr = exg<MC>(re),      ci = exg<MC>(im);
    float dr = exg<MB | MC>(re), di = exg<MB | MC>(im);
    float nr, ni;
    ringapply(c, re, im, br, bi, cr, ci, dr, di, nr, ni);
    re = nr; im = ni;
}

// ---------------------------------------------------------------------------
// prep_kernel: stores hc = 0.5/(2pi)*cos, hs = 0.5/(2pi)*sin in rec[6..17]
// (folds BOTH the 0.5 of sincos(h/2) AND the revolutions conversion for
// v_sin/v_cos into the recurrence coefficients). Compensated by 4pi on Cc
// rows 0-5 and 12-17 (px and h' output coefficients): 4pi * 0.5/(2pi) = 1.
// Y coefficients (rows 6-11) unchanged.
// ---------------------------------------------------------------------------
__global__ __launch_bounds__(256) void prep_kernel(
    const float* __restrict__ angles, const float* __restrict__ Wx,
    const float* __restrict__ Wdt, const float* __restrict__ bdt,
    const float* __restrict__ D, const float* __restrict__ Wc,
    float* __restrict__ sd)
{
    int gid = blockIdx.x * blockDim.x + threadIdx.x;
    if (gid >= BATCH * SEQ) return;
    const float* a = angles + (size_t)gid * 6;
    float ang[6];
#pragma unroll
    for (int i = 0; i < 6; i++) ang[i] = a[i];
    float dtr[3];
#pragma unroll
    for (int r = 0; r < 3; r++) {
        float s = 0.f;
#pragma unroll
        for (int k = 0; k < 6; k++) s += ang[k] * Wx[r * 6 + k];
        dtr[r] = s;
    }
    float* rec = sd + (size_t)gid * SDS;
    float dtv[6];
#pragma unroll
    for (int i = 0; i < 6; i++) {
        float x = bdt[i];
#pragma unroll
        for (int r = 0; r < 3; r++) x += dtr[r] * Wdt[i * 3 + r];
        float sp = (x > 15.f) ? x : log1pf(expf(x));
        dtv[i] = tanhf(sp) * PI_F;
        rec[i] = dtv[i];
        float th = ang[i] * dtv[i];
        rec[6 + i]  = K_HALF_INV2PI * cosf(th);
        rec[12 + i] = K_HALF_INV2PI * sinf(th);
    }
    float C[6];
#pragma unroll
    for (int i = 0; i < 6; i++) {
        float s = 0.f;
#pragma unroll
        for (int k = 0; k < 6; k++) s += ang[k] * Wx[(9 + i) * 6 + k];
        C[i] = s;
    }
#pragma unroll
    for (int j = 0; j < 18; j++) {
        float s = 0.f;
#pragma unroll
        for (int i = 0; i < 6; i++) s += C[i] * Wc[j * 6 + i];
        rec[18 + j] = (j < 6 || j >= 12) ? FOURPI_F * s : s;
        rec[36 + j] = D[j] * ang[j % 6];
    }
}

// ---------------------------------------------------------------------------
// step_kernel v5: ONE wave per batch element (grid 256 x 64). ZERO LDS,
// ZERO barriers, ZERO inter-wave exchange. U is applied per step as its
// 18-stage gate chain in-register (same per-lane coefficients and exchange
// masks as the verified umat_kernel; by linearity the chain maps psi -> U psi).
// Z via WHT butterfly; X,Y via direct signed correlations; h recurrence
// in-wave. Records prefetched 2 ahead; QSVT phase sincos precomputed 1 ahead.
// ---------------------------------------------------------------------------
__global__ __launch_bounds__(64, 1) void step_kernel(
    const float* __restrict__ sd, const float* __restrict__ pcf,
    const float* __restrict__ qp, const float* __restrict__ cp,
    float* __restrict__ out)
{
    const int lane = threadIdx.x;
    const int b = blockIdx.x;

    int bitv[6];
#pragma unroll
    for (int i = 0; i < 6; i++) bitv[i] = (lane >> (5 - i)) & 1;
    int sflip[6];
    float sgnf[6];
#pragma unroll
    for (int q = 0; q < 6; q++) {
        sflip[q] = bitv[q] ? (int)0x80000000 : 0;
        sgnf[q]  = bitv[q] ? -1.f : 1.f;
    }
    const float w0 = bitv[0] ? -2.f : 0.f;   // permlane-sum butterfly weights
    const float w1 = bitv[1] ? -2.f : 0.f;

    // ---- per-lane gate coefficients (ported verbatim from umat_kernel) ----
    float qc[2][3][8], rc[2][6][4];
#pragma unroll
    for (int l = 0; l < 2; l++) {
        float g00r[6], g00i[6], g01r[6], g01i[6], g10r[6], g10i[6], g11r[6], g11i[6];
#pragma unroll
        for (int i = 0; i < 6; i++) {
            float ax = cp[l * 30 + i * 3 + 0];
            float ay = cp[l * 30 + i * 3 + 1];
            float az = cp[l * 30 + i * 3 + 2];
            float ca = cosf(0.5f * ax), sa = sinf(0.5f * ax);
            float cb = cosf(0.5f * ay), sb = sinf(0.5f * ay);
            float cg = cosf(0.5f * az), sg = sinf(0.5f * az);
            float m00r = cb * ca, m00i =  sb * sa;
            float m01r = -sb * ca, m01i = -cb * sa;
            float m10r =  sb * ca, m10i = -cb * sa;
            float m11r =  cb * ca, m11i = -sb * sa;
            g00r[i] = cg * m00r + sg * m00i; g00i[i] = cg * m00i - sg * m00r;
            g01r[i] = cg * m01r + sg * m01i; g01i[i] = cg * m01i - sg * m01r;
            g10r[i] = cg * m10r - sg * m10i; g10i[i] = cg * m10i + sg * m10r;
            g11r[i] = cg * m11r - sg * m11i; g11i[i] = cg * m11i + sg * m11r;
        }
#pragma unroll
        for (int pp = 0; pp < 3; pp++) {
            int aq = 2 * pp, bq = 2 * pp + 1;
            float dar = bitv[aq] ? g11r[aq] : g00r[aq], dai = bitv[aq] ? g11i[aq] : g00i[aq];
            float oar = bitv[aq] ? g10r[aq] : g01r[aq], oai = bitv[aq] ? g10i[aq] : g01i[aq];
            float dbr = bitv[bq] ? g11r[bq] : g00r[bq], dbi = bitv[bq] ? g11i[bq] : g00i[bq];
            float obr = bitv[bq] ? g10r[bq] : g01r[bq], obi = bitv[bq] ? g10i[bq] : g01i[bq];
            qc[l][pp][0] = dar * dbr - dai * dbi;  qc[l][pp][1] = dar * dbi + dai * dbr;
            qc[l][pp][2] = oar * dbr - oai * dbi;  qc[l][pp][3] = oar * dbi + oai * dbr;
            qc[l][pp][4] = dar * obr - dai * obi;  qc[l][pp][5] = dar * obi + dai * obr;
            qc[l][pp][6] = oar * obr - oai * obi;  qc[l][pp][7] = oar * obi + oai * obr;
        }
        const int Aq[6] = {0, 2, 4, 5, 3, 1};
        const int Bq[6] = {1, 3, 5, 4, 2, 0};
#pragma unroll
        for (int o = 0; o < 6; o++) {
            float tha = (o < 3) ? cp[l * 30 + 18 + 2 * o]     : cp[l * 30 + 24 + 2 * (o - 3)];
            float thb = (o < 3) ? cp[l * 30 + 18 + 2 * o + 1] : cp[l * 30 + 24 + 2 * (o - 3) + 1];
            float ca = cosf(0.5f * tha), sa = sinf(0.5f * tha);
            float cb = cosf(0.5f * thb), sb = sinf(0.5f * thb);
            int ba = bitv[Aq[o]], bb = bitv[Bq[o]];
            float mx0 = ba ? ca : 1.f, sae = ba ? sa : 0.f;
            float ny0 = bb ? cb : 1.f, sbe = bb ? sb : 0.f;
            rc[l][o][0] = ny0 * mx0; rc[l][o][1] = -ny0 * sae;
            rc[l][o][2] = -mx0 * sbe; rc[l][o][3] = -sae * sbe;
        }
    }

    // QSVT collapse: per-lane phase coefs (pre-scaled to revolutions) +
    // permuted product-state selects
    float A[6], sel[6];
    {
        int x1 = permf(lane), x2 = permf(x1), x3 = permf(x2), x4 = permf(x3);
#pragma unroll
        for (int i = 0; i < 6; i++) {
            float u0 = pcf[0] * PI_F * qp[0 * 6 + i];
            float u1 = pcf[1] * PI_F * qp[1 * 6 + i];
            float u2 = pcf[2] * PI_F * qp[2 * 6 + i];
            float u3 = pcf[3] * PI_F;
            float t1 = ((x1 >> (5 - i)) & 1) ? 0.5f : -0.5f;
            float t2 = ((x2 >> (5 - i)) & 1) ? 0.5f : -0.5f;
            float t3 = ((x3 >> (5 - i)) & 1) ? 0.5f : -0.5f;
            float t4 = ((x4 >> (5 - i)) & 1) ? 0.5f : -0.5f;
            A[i] = (u3 * t1 + u2 * t2 + u1 * t3 + u0 * t4) * INV2PI_F;
            sel[i] = (float)((x4 >> (5 - i)) & 1);
        }
    }

    // 6-stage WHT butterfly, fully VALU: lane m ends with sum_j (-1)^{m.j} v_j
    auto b6 = [&](float v) -> float {
        float g;
        g = exg<1>(v); v = fmaf(sgnf[5], v, g);
        g = exg<2>(v); v = fmaf(sgnf[4], v, g);
        g = exg<4>(v); v = fmaf(sgnf[3], v, g);
        g = exg<8>(v); v = fmaf(sgnf[2], v, g);
        v = fmaf(w1, v, sum16(v));
        v = fmaf(w0, v, sum32(v));
        return v;
    };

    const float* sdb = sd + (size_t)b * SEQ * SDS;
    float* outb = out + (size_t)b * SEQ * 18;

    // hh = h/(4pi): sincos args in revolutions (folded into rec[6..17] by prep)
    float hh0 = 0.f, hh1 = 0.f, hh2 = 0.f, hh3 = 0.f, hh4 = 0.f, hh5 = 0.f;

    // 3 rotating record buffers (2-ahead prefetch): d[6], hc[6], hs[6]
    float buf0[18], buf1[18], buf2[18];
    auto ldrec = [&](float (&dst)[18], int t) {
        const float2* p2 = (const float2*)(sdb + (size_t)t * SDS);
#pragma unroll
        for (int k = 0; k < 9; k++) {
            float2 v = p2[k];
            dst[2 * k] = v.x; dst[2 * k + 1] = v.y;
        }
    };
    ldrec(buf0, 0);
    ldrec(buf1, 1);

    // phase sincos for the step about to execute
    float sphC, cphC;
    {
        float u = A[0]*buf0[0] + A[1]*buf0[1] + A[2]*buf0[2]
                + A[3]*buf0[3] + A[4]*buf0[4] + A[5]*buf0[5];
        u = u - floorf(u);
        sphC = __builtin_amdgcn_sinf(u);
        cphC = __builtin_amdgcn_cosf(u);
    }

    auto body = [&](float (&cur)[18], float (&nxt)[18], float (&far)[18], int t) {
        // prefetch record t+2 (vmem latency hidden under ~2 steps of compute)
        ldrec(far, (t + 2 < SEQ) ? t + 2 : SEQ - 1);

        // ---- product state RY(h)|0..0>, pre-permuted via sel bits ----
        float ss0 = __builtin_amdgcn_sinf(hh0), cc0 = __builtin_amdgcn_cosf(hh0);
        float ss1 = __builtin_amdgcn_sinf(hh1), cc1 = __builtin_amdgcn_cosf(hh1);
        float ss2 = __builtin_amdgcn_sinf(hh2), cc2 = __builtin_amdgcn_cosf(hh2);
        float ss3 = __builtin_amdgcn_sinf(hh3), cc3 = __builtin_amdgcn_cosf(hh3);
        float ss4 = __builtin_amdgcn_sinf(hh4), cc4 = __builtin_amdgcn_cosf(hh4);
        float ss5 = __builtin_amdgcn_sinf(hh5), cc5 = __builtin_amdgcn_cosf(hh5);
        float f0 = fmaf(sel[0], ss0 - cc0, cc0);
        float f1 = fmaf(sel[1], ss1 - cc1, cc1);
        float f2 = fmaf(sel[2], ss2 - cc2, cc2);
        float f3 = fmaf(sel[3], ss3 - cc3, cc3);
        float f4 = fmaf(sel[4], ss4 - cc4, cc4);
        float f5 = fmaf(sel[5], ss5 - cc5, cc5);
        float prod = ((f0 * f1) * (f2 * f3)) * (f4 * f5);
        float re = prod * cphC, im = prod * sphC;

        // ---- precompute next step's phase from nxt (loaded 1 body ago) ----
        {
            float u = A[0]*nxt[0] + A[1]*nxt[1] + A[2]*nxt[2]
                    + A[3]*nxt[3] + A[4]*nxt[4] + A[5]*nxt[5];
            u = u - floorf(u);
            sphC = __builtin_amdgcn_sinf(u);
            cphC = __builtin_amdgcn_cosf(u);
        }

        // ---- apply U: 18 in-register gate stages (umat chain on the state) --
#pragma unroll
        for (int l = 0; l < 2; l++) {
            p1qS<32, 16>(re, im, qc[l][0]);
            p1qS<8, 4>(re, im, qc[l][1]);
            p1qS<2, 1>(re, im, qc[l][2]);
            rngS<16, 8>(re, im, rc[l][0]);
            rngS<4, 2>(re, im, rc[l][1]);
            rngS<1, 32>(re, im, rc[l][2]);
            rngS<2, 4>(re, im, rc[l][3]);
            rngS<8, 16>(re, im, rc[l][4]);
            rngS<32, 1>(re, im, rc[l][5]);
        }

        // ---- Z via WHT butterfly ----
        float P  = fmaf(re, re, im * im);
        float Wp = b6(P);                       // lane 32>>q holds Z_q
        float Z0 = rdl<32>(Wp), Z1 = rdl<16>(Wp), Z2 = rdl<8>(Wp);
        float Z3 = rdl<4>(Wp),  Z4 = rdl<2>(Wp),  Z5 = rdl<1>(Wp);

        // ---- partner states for all 6 masks ----
        float g32r = exg<32>(re), g32i = exg<32>(im);
        float g16r = exg<16>(re), g16i = exg<16>(im);
        float g8r  = exg<8>(re),  g8i  = exg<8>(im);
        float g4r  = exg<4>(re),  g4i  = exg<4>(im);
        float g2r  = exg<2>(re),  g2i  = exg<2>(im);
        float g1r  = exg<1>(re),  g1i  = exg<1>(im);

        // ---- X via direct correlations (uniform results) ----
        float X0 = redsum64(fmaf(re, g32r, im * g32i));
        float X1 = redsum64(fmaf(re, g16r, im * g16i));
        float X2 = redsum64(fmaf(re, g8r,  im * g8i));
        float X3 = redsum64(fmaf(re, g4r,  im * g4i));
        float X4 = redsum64(fmaf(re, g2r,  im * g2i));
        float X5 = redsum64(fmaf(re, g1r,  im * g1i));

        // ---- h recurrence (cur[6..17] pre-scaled by 0.5/(2pi)) ----
        hh0 = cur[6]  * Z0 - cur[12] * X0;
        hh1 = cur[7]  * Z1 - cur[13] * X1;
        hh2 = cur[8]  * Z2 - cur[14] * X2;
        hh3 = cur[9]  * Z3 - cur[15] * X3;
        hh4 = cur[10] * Z4 - cur[16] * X4;
        hh5 = cur[11] * Z5 - cur[17] * X5;

        // ---- Y (output only) ----
        float Y0 = redsum64(xorf(fmaf(re, g32i, -(im * g32r)), sflip[0]));
        float Y1 = redsum64(xorf(fmaf(re, g16i, -(im * g16r)), sflip[1]));
        float Y2 = redsum64(xorf(fmaf(re, g8i,  -(im * g8r)),  sflip[2]));
        float Y3 = redsum64(xorf(fmaf(re, g4i,  -(im * g4r)),  sflip[3]));
        float Y4 = redsum64(xorf(fmaf(re, g2i,  -(im * g2r)),  sflip[4]));
        float Y5 = redsum64(xorf(fmaf(re, g1i,  -(im * g1r)),  sflip[5]));

        // ---- store raw Z/X/Y (finalized by post_kernel) ----
        if (lane == 0) {
            float2* o2 = (float2*)(outb + (size_t)t * 18);
            o2[0] = make_float2(Z0, Z1); o2[1] = make_float2(Z2, Z3);
            o2[2] = make_float2(Z4, Z5); o2[3] = make_float2(X0, X1);
            o2[4] = make_float2(X2, X3); o2[5] = make_float2(X4, X5);
            o2[6] = make_float2(Y0, Y1); o2[7] = make_float2(Y2, Y3);
            o2[8] = make_float2(Y4, Y5);
        }
    };

    for (int t = 0; t < 510; t += 3) {
        body(buf0, buf1, buf2, t);
        body(buf1, buf2, buf0, t + 1);
        body(buf2, buf0, buf1, t + 2);
    }
    body(buf0, buf1, buf2, 510);
    body(buf1, buf2, buf0, 511);
}

// ---------------------------------------------------------------------------
// post_kernel: finalize outputs in place over the raw Z/X/Y. rec holds
// hc = 0.5/(2pi)*cos, hs = 0.5/(2pi)*sin and 4pi-scaled Cc on the px/h'
// rows — the folded constants cancel exactly (4pi * 0.5/(2pi) = 1), so the
// results are value-identical to the original formulas.
// ---------------------------------------------------------------------------
__global__ __launch_bounds__(256) void post_kernel(
    const float* __restrict__ sd, float* __restrict__ out)
{
    int gid = blockIdx.x * blockDim.x + threadIdx.x;
    if (gid >= BATCH * SEQ) return;
    const float* rec = sd + (size_t)gid * SDS;
    float* o = out + (size_t)gid * 18;

    float zxy[18];
    {
        const float2* o2 = (const float2*)o;
#pragma unroll
        for (int k = 0; k < 9; k++) {
            float2 v = o2[k];
            zxy[2 * k] = v.x; zxy[2 * k + 1] = v.y;
        }
    }
    float r[54];
    {
        const float2* r2 = (const float2*)rec;
#pragma unroll
        for (int k = 3; k < 27; k++) {       // floats 6..53 (hc,hs,Cc,term)
            float2 v = r2[k];
            r[2 * k] = v.x; r[2 * k + 1] = v.y;
        }
    }
    float res[18];
#pragma unroll
    for (int q = 0; q < 6; q++) {
        float Z = zxy[q], X = zxy[6 + q], Y = zxy[12 + q];
        float c = r[6 + q], s = r[12 + q];   // = 0.5/(2pi) * {cos, sin}
        float px = c * X + s * Z;
        float hq = c * Z - s * X;
        res[q]      = fmaf(r[18 + q], px, r[36 + q]);   // r18 = 4pi*Cc
        res[6 + q]  = fmaf(r[24 + q], Y,  r[42 + q]);   // unscaled
        res[12 + q] = fmaf(r[30 + q], hq, r[48 + q]);   // r30 = 4pi*Cc
    }
    float2* ow = (float2*)o;
#pragma unroll
    for (int k = 0; k < 9; k++) ow[k] = make_float2(res[2 * k], res[2 * k + 1]);
}

// ---------------------------------------------------------------------------
extern "C" void kernel_launch(void* const* d_in, const int* in_sizes, int n_in,
                              void* d_out, int out_size, void* d_ws, size_t ws_size,
                              hipStream_t stream) {
    const float* angles = (const float*)d_in[0];
    const float* Wx     = (const float*)d_in[1];
    const float* Wdt    = (const float*)d_in[2];
    const float* bdt    = (const float*)d_in[3];
    const float* pc     = (const float*)d_in[4];
    const float* qp     = (const float*)d_in[5];
    const float* cp     = (const float*)d_in[6];
    const float* D      = (const float*)d_in[7];
    const float* Wc     = (const float*)d_in[8];
    float* sd  = (float*)d_ws;                                // 28.3 MB
    float* out = (float*)d_out;

    prep_kernel<<<(BATCH * SEQ) / 256, 256, 0, stream>>>(angles, Wx, Wdt, bdt, D, Wc, sd);
    step_kernel<<<BATCH, 64, 0, stream>>>(sd, pc, qp, cp, out);
    post_kernel<<<(BATCH * SEQ) / 256, 256, 0, stream>>>(sd, out);
}

// Round 7
// 961.976 us; speedup vs baseline: 1.1139x; 1.1139x over previous
//
#include <hip/hip_runtime.h>
#include <math.h>

#define BATCH 256
#define SEQ 512
#define SDS 54            // floats per (b,t) record: dt[6] hc[6] hs[6] Cc[18] term[18]
#define PI_F 3.14159265358979323846f
#define INV2PI_F 0.15915494309189535f
#define K_HALF_INV2PI 0.07957747154594767f   // 0.5/(2*pi)
#define FOURPI_F 12.566370614359172f

// ---- cross-lane helpers (ALL VALU — no LDS pipe anywhere) -------------------
template<int CTRL>
__device__ __forceinline__ float fdpp(float v) {
    return __int_as_float(__builtin_amdgcn_mov_dpp(__float_as_int(v), CTRL, 0xF, 0xF, true));
}
template<int L>
__device__ __forceinline__ float rdl(float v) {
    return __int_as_float(__builtin_amdgcn_readlane(__float_as_int(v), L));
}
template<int M>
__device__ __forceinline__ float swz(float v) {   // fallback only
    return __int_as_float(__builtin_amdgcn_ds_swizzle(__float_as_int(v), (M << 10) | 0x1F));
}
// sum with xor-16 / xor-32 partner, direction-proof: r[0]+r[1] == v[l]+v[l^m]
// in either swap convention of v_permlane*_swap_b32. (validated R1-R4)
#if __has_builtin(__builtin_amdgcn_permlane16_swap)
__device__ __forceinline__ float sum16(float v) {
    typedef unsigned int u2v __attribute__((ext_vector_type(2)));
    u2v r = __builtin_amdgcn_permlane16_swap(__float_as_uint(v), __float_as_uint(v), false, false);
    return __uint_as_float(r[0]) + __uint_as_float(r[1]);
}
#else
__device__ __forceinline__ float sum16(float v) { return v + swz<16>(v); }
#endif
#if __has_builtin(__builtin_amdgcn_permlane32_swap)
__device__ __forceinline__ float sum32(float v) {
    typedef unsigned int u2v __attribute__((ext_vector_type(2)));
    u2v r = __builtin_amdgcn_permlane32_swap(__float_as_uint(v), __float_as_uint(v), false, false);
    return __uint_as_float(r[0]) + __uint_as_float(r[1]);
}
#else
__device__ __forceinline__ float sum32(float v) { return v + __shfl_xor(v, 32, 64); }
#endif
// generic xor-M lane exchange, VALU-only (validated primitives from R2-R4)
template<int M>
__device__ __forceinline__ float exg(float v) {
    if constexpr (M == 1)       return fdpp<0xB1>(v);              // quad_perm 1032
    else if constexpr (M == 2)  return fdpp<0x4E>(v);              // quad_perm 2301
    else if constexpr (M == 3)  return fdpp<0x1B>(v);              // quad_perm 3210
    else if constexpr (M == 4)  return fdpp<0x141>(fdpp<0x1B>(v)); // half_mirror∘xor3
    else if constexpr (M == 6)  return fdpp<0x4E>(exg<4>(v));      // xor2∘xor4
    else if constexpr (M == 8)  return fdpp<0x128>(v);             // row_ror8 ≡ xor8
    else if constexpr (M == 12) return exg<4>(fdpp<0x128>(v));     // xor4∘xor8
    else if constexpr (M == 16) return sum16(v) - v;
    else if constexpr (M == 24) return fdpp<0x128>(sum16(v) - v);  // xor8∘xor16
    else if constexpr (M == 32) return sum32(v) - v;
    else if constexpr (M == 33) { float w = fdpp<0xB1>(v); return sum32(w) - w; }
    else if constexpr (M == 48) { float w = sum16(v) - v; return sum32(w) - w; }
    else                        return swz<M>(v);
}
// full 64-lane sum, uniform in every lane, fully VALU
__device__ __forceinline__ float redsum64(float v) {
    v += fdpp<0x128>(v);
    v += fdpp<0x124>(v);
    v += fdpp<0x122>(v);
    v += fdpp<0x121>(v);           // every lane: its row16 sum
    v = sum16(v);                  // + partner row
    v = sum32(v);                  // + other half
    return v;
}
__device__ __forceinline__ float xorf(float v, int m) {
    return __int_as_float(__float_as_int(v) ^ m);
}
// QSVT per-degree CNOT-block permutation (GF(2)-linear) — verified R1-R6
__device__ __forceinline__ int permf(int x) {
    const int cs[11] = {0,1,2,3,4,5,5,4,3,2,1};
    const int ts[11] = {1,2,3,4,5,0,4,3,2,1,0};
#pragma unroll
    for (int k = 10; k >= 0; k--) {
        int cb = (x >> (5 - cs[k])) & 1;
        x ^= cb << (5 - ts[k]);
    }
    return x;
}

// ---- gate-stage appliers: REAL functions, coefficients BY VALUE -------------
// (R4's regression: passing const float* made qc/rc addressable -> scratch.
//  By-value scalars + constant-index reads let SROA keep arrays in registers.
//  Math identical to the R4-verified chain; trees balanced.)
template<int MI, int MJ, int MK>
__device__ __forceinline__ void p1qv(float& re, float& im,
    float c0, float c1, float c2, float c3,
    float c4, float c5, float c6, float c7)
{
    float ar = exg<MI>(re), ai = exg<MI>(im);
    float br = exg<MJ>(re), bi = exg<MJ>(im);
    float cr = exg<MK>(re), ci = exg<MK>(im);
    float t0 = fmaf(-c1, im, c0 * re);
    float t1 = fmaf(-c3, ai, c2 * ar);
    float t2 = fmaf(-c5, bi, c4 * br);
    float t3 = fmaf(-c7, ci, c6 * cr);
    float u0 = fmaf(c1, re, c0 * im);
    float u1 = fmaf(c3, ar, c2 * ai);
    float u2 = fmaf(c5, br, c4 * bi);
    float u3 = fmaf(c7, cr, c6 * ci);
    re = (t0 + t1) + (t2 + t3);
    im = (u0 + u1) + (u2 + u3);
}
template<int MB, int MC, int MD>
__device__ __forceinline__ void rngv(float& re, float& im,
    float c0, float c1, float c2, float c3)
{
    float br = exg<MB>(re), bi = exg<MB>(im);
    float cr = exg<MC>(re), ci = exg<MC>(im);
    float dr = exg<MD>(re), di = exg<MD>(im);
    float t0 = fmaf(-c1, bi, c0 * re);
    float t1 = fmaf(c3, dr, -(c2 * ci));
    float u0 = fmaf(c1, br, c0 * im);
    float u1 = fmaf(c3, di, c2 * cr);
    re = t0 + t1;
    im = u0 + u1;
}
// element-list expansion (expands in a FUNCTION call — no macro-arity issue)
#define QARGS(l,p) qc[l][p][0],qc[l][p][1],qc[l][p][2],qc[l][p][3],qc[l][p][4],qc[l][p][5],qc[l][p][6],qc[l][p][7]
#define RARGS(l,o) rc[l][o][0],rc[l][o][1],rc[l][o][2],rc[l][o][3]

// ---------------------------------------------------------------------------
// prep_kernel: stores hc = 0.5/(2pi)*cos, hs = 0.5/(2pi)*sin in rec[6..17]
// (folds the 0.5 of sincos(h/2) AND the revolutions conversion), compensated
// by 4pi on Cc rows 0-5 and 12-17. (R4-verified)
// ---------------------------------------------------------------------------
__global__ __launch_bounds__(256) void prep_kernel(
    const float* __restrict__ angles, const float* __restrict__ Wx,
    const float* __restrict__ Wdt, const float* __restrict__ bdt,
    const float* __restrict__ D, const float* __restrict__ Wc,
    float* __restrict__ sd)
{
    int gid = blockIdx.x * blockDim.x + threadIdx.x;
    if (gid >= BATCH * SEQ) return;
    const float* a = angles + (size_t)gid * 6;
    float ang[6];
#pragma unroll
    for (int i = 0; i < 6; i++) ang[i] = a[i];
    float dtr[3];
#pragma unroll
    for (int r = 0; r < 3; r++) {
        float s = 0.f;
#pragma unroll
        for (int k = 0; k < 6; k++) s += ang[k] * Wx[r * 6 + k];
        dtr[r] = s;
    }
    float* rec = sd + (size_t)gid * SDS;
    float dtv[6];
#pragma unroll
    for (int i = 0; i < 6; i++) {
        float x = bdt[i];
#pragma unroll
        for (int r = 0; r < 3; r++) x += dtr[r] * Wdt[i * 3 + r];
        float sp = (x > 15.f) ? x : log1pf(expf(x));
        dtv[i] = tanhf(sp) * PI_F;
        rec[i] = dtv[i];
        float th = ang[i] * dtv[i];
        rec[6 + i]  = K_HALF_INV2PI * cosf(th);
        rec[12 + i] = K_HALF_INV2PI * sinf(th);
    }
    float C[6];
#pragma unroll
    for (int i = 0; i < 6; i++) {
        float s = 0.f;
#pragma unroll
        for (int k = 0; k < 6; k++) s += ang[k] * Wx[(9 + i) * 6 + k];
        C[i] = s;
    }
#pragma unroll
    for (int j = 0; j < 18; j++) {
        float s = 0.f;
#pragma unroll
        for (int i = 0; i < 6; i++) s += C[i] * Wc[j * 6 + i];
        rec[18 + j] = (j < 6 || j >= 12) ? FOURPI_F * s : s;
        rec[36 + j] = D[j] * ang[j % 6];
    }
}

// ---------------------------------------------------------------------------
// step_kernel v6b: 4 waves/block (one per SIMD), each wave REDUNDANTLY runs
// the full h-path — product state, 18-stage in-register gate chain (the
// R4-verified umat chain applied to the state), WHT Z, correlation X, h.
// ZERO LDS, ZERO barriers, ZERO readlane-matvec. Y + stores split by wave.
// ---------------------------------------------------------------------------
__global__ __launch_bounds__(256, 1) void step_kernel(
    const float* __restrict__ sd, const float* __restrict__ pcf,
    const float* __restrict__ qp, const float* __restrict__ cp,
    float* __restrict__ out)
{
    const int tid = threadIdx.x;
    const int wave = tid >> 6;
    const int lane = tid & 63;
    const int b = blockIdx.x;

    int bitv[6];
#pragma unroll
    for (int i = 0; i < 6; i++) bitv[i] = (lane >> (5 - i)) & 1;
    int sflip[6];
    float sgnf[6];
#pragma unroll
    for (int q = 0; q < 6; q++) {
        sflip[q] = bitv[q] ? (int)0x80000000 : 0;
        sgnf[q]  = bitv[q] ? -1.f : 1.f;
    }
    const float w0 = bitv[0] ? -2.f : 0.f;   // permlane-sum butterfly weights
    const float w1 = bitv[1] ? -2.f : 0.f;

    // ---- per-lane gate coefficients (R4-verified construction) ----
    float qc[2][3][8], rc[2][6][4];
#pragma unroll
    for (int l = 0; l < 2; l++) {
        float g00r[6], g00i[6], g01r[6], g01i[6], g10r[6], g10i[6], g11r[6], g11i[6];
#pragma unroll
        for (int i = 0; i < 6; i++) {
            float ax = cp[l * 30 + i * 3 + 0];
            float ay = cp[l * 30 + i * 3 + 1];
            float az = cp[l * 30 + i * 3 + 2];
            float ca = cosf(0.5f * ax), sa = sinf(0.5f * ax);
            float cb = cosf(0.5f * ay), sb = sinf(0.5f * ay);
            float cg = cosf(0.5f * az), sg = sinf(0.5f * az);
            float m00r = cb * ca, m00i =  sb * sa;
            float m01r = -sb * ca, m01i = -cb * sa;
            float m10r =  sb * ca, m10i = -cb * sa;
            float m11r =  cb * ca, m11i = -sb * sa;
            g00r[i] = cg * m00r + sg * m00i; g00i[i] = cg * m00i - sg * m00r;
            g01r[i] = cg * m01r + sg * m01i; g01i[i] = cg * m01i - sg * m01r;
            g10r[i] = cg * m10r - sg * m10i; g10i[i] = cg * m10i + sg * m10r;
            g11r[i] = cg * m11r - sg * m11i; g11i[i] = cg * m11i + sg * m11r;
        }
#pragma unroll
        for (int pp = 0; pp < 3; pp++) {
            int aq = 2 * pp, bq = 2 * pp + 1;
            float dar = bitv[aq] ? g11r[aq] : g00r[aq], dai = bitv[aq] ? g11i[aq] : g00i[aq];
            float oar = bitv[aq] ? g10r[aq] : g01r[aq], oai = bitv[aq] ? g10i[aq] : g01i[aq];
            float dbr = bitv[bq] ? g11r[bq] : g00r[bq], dbi = bitv[bq] ? g11i[bq] : g00i[bq];
            float obr = bitv[bq] ? g10r[bq] : g01r[bq], obi = bitv[bq] ? g10i[bq] : g01i[bq];
            qc[l][pp][0] = dar * dbr - dai * dbi;  qc[l][pp][1] = dar * dbi + dai * dbr;
            qc[l][pp][2] = oar * dbr - oai * dbi;  qc[l][pp][3] = oar * dbi + oai * dbr;
            qc[l][pp][4] = dar * obr - dai * obi;  qc[l][pp][5] = dar * obi + dai * obr;
            qc[l][pp][6] = oar * obr - oai * obi;  qc[l][pp][7] = oar * obi + oai * obr;
        }
        const int Aq[6] = {0, 2, 4, 5, 3, 1};
        const int Bq[6] = {1, 3, 5, 4, 2, 0};
#pragma unroll
        for (int o = 0; o < 6; o++) {
            float tha = (o < 3) ? cp[l * 30 + 18 + 2 * o]     : cp[l * 30 + 24 + 2 * (o - 3)];
            float thb = (o < 3) ? cp[l * 30 + 18 + 2 * o + 1] : cp[l * 30 + 24 + 2 * (o - 3) + 1];
            float ca = cosf(0.5f * tha), sa = sinf(0.5f * tha);
            float cb = cosf(0.5f * thb), sb = sinf(0.5f * thb);
            int ba = bitv[Aq[o]], bb = bitv[Bq[o]];
            float mx0 = ba ? ca : 1.f, sae = ba ? sa : 0.f;
            float ny0 = bb ? cb : 1.f, sbe = bb ? sb : 0.f;
            rc[l][o][0] = ny0 * mx0; rc[l][o][1] = -ny0 * sae;
            rc[l][o][2] = -mx0 * sbe; rc[l][o][3] = -sae * sbe;
        }
    }

    // QSVT collapse: per-lane phase coefs (revolutions) + permuted selects
    float A[6], sel[6];
    {
        int x1 = permf(lane), x2 = permf(x1), x3 = permf(x2), x4 = permf(x3);
#pragma unroll
        for (int i = 0; i < 6; i++) {
            float u0 = pcf[0] * PI_F * qp[0 * 6 + i];
            float u1 = pcf[1] * PI_F * qp[1 * 6 + i];
            float u2 = pcf[2] * PI_F * qp[2 * 6 + i];
            float u3 = pcf[3] * PI_F;
            float t1 = ((x1 >> (5 - i)) & 1) ? 0.5f : -0.5f;
            float t2 = ((x2 >> (5 - i)) & 1) ? 0.5f : -0.5f;
            float t3 = ((x3 >> (5 - i)) & 1) ? 0.5f : -0.5f;
            float t4 = ((x4 >> (5 - i)) & 1) ? 0.5f : -0.5f;
            A[i] = (u3 * t1 + u2 * t2 + u1 * t3 + u0 * t4) * INV2PI_F;
            sel[i] = (float)((x4 >> (5 - i)) & 1);
        }
    }

    // 6-stage WHT butterfly, fully VALU: lane m ends with sum_j (-1)^{m.j} v_j
    auto b6 = [&](float v) -> float {
        float g;
        g = exg<1>(v); v = fmaf(sgnf[5], v, g);
        g = exg<2>(v); v = fmaf(sgnf[4], v, g);
        g = exg<4>(v); v = fmaf(sgnf[3], v, g);
        g = exg<8>(v); v = fmaf(sgnf[2], v, g);
        v = fmaf(w1, v, sum16(v));
        v = fmaf(w0, v, sum32(v));
        return v;
    };

    const float* sdb = sd + (size_t)b * SEQ * SDS;
    float* outb = out + (size_t)b * SEQ * 18;

    // hh = h/(4pi): sincos args in revolutions (folded into rec[6..17] by prep)
    float hh0 = 0.f, hh1 = 0.f, hh2 = 0.f, hh3 = 0.f, hh4 = 0.f, hh5 = 0.f;

    // 3 rotating record buffers (2-ahead prefetch): d[6], hc[6], hs[6]
    float buf0[18], buf1[18], buf2[18];
    auto ldrec = [&](float (&dst)[18], int t) {
        const float2* p2 = (const float2*)(sdb + (size_t)t * SDS);
#pragma unroll
        for (int k = 0; k < 9; k++) {
            float2 v = p2[k];
            dst[2 * k] = v.x; dst[2 * k + 1] = v.y;
        }
    };
    ldrec(buf0, 0);
    ldrec(buf1, 1);

    // phase sincos for the step about to execute
    float sphC, cphC;
    {
        float u = A[0]*buf0[0] + A[1]*buf0[1] + A[2]*buf0[2]
                + A[3]*buf0[3] + A[4]*buf0[4] + A[5]*buf0[5];
        u = u - floorf(u);
        sphC = __builtin_amdgcn_sinf(u);
        cphC = __builtin_amdgcn_cosf(u);
    }

    auto body = [&](float (&cur)[18], float (&nxt)[18], float (&far)[18], int t) {
        // prefetch record t+2 (vmem latency hidden under ~2 steps of compute)
        ldrec(far, (t + 2 < SEQ) ? t + 2 : SEQ - 1);

        // ---- product state RY(h)|0..0>, pre-permuted via sel bits ----
        float ss0 = __builtin_amdgcn_sinf(hh0), cc0 = __builtin_amdgcn_cosf(hh0);
        float ss1 = __builtin_amdgcn_sinf(hh1), cc1 = __builtin_amdgcn_cosf(hh1);
        float ss2 = __builtin_amdgcn_sinf(hh2), cc2 = __builtin_amdgcn_cosf(hh2);
        float ss3 = __builtin_amdgcn_sinf(hh3), cc3 = __builtin_amdgcn_cosf(hh3);
        float ss4 = __builtin_amdgcn_sinf(hh4), cc4 = __builtin_amdgcn_cosf(hh4);
        float ss5 = __builtin_amdgcn_sinf(hh5), cc5 = __builtin_amdgcn_cosf(hh5);
        float f0 = fmaf(sel[0], ss0 - cc0, cc0);
        float f1 = fmaf(sel[1], ss1 - cc1, cc1);
        float f2 = fmaf(sel[2], ss2 - cc2, cc2);
        float f3 = fmaf(sel[3], ss3 - cc3, cc3);
        float f4 = fmaf(sel[4], ss4 - cc4, cc4);
        float f5 = fmaf(sel[5], ss5 - cc5, cc5);
        float prod = ((f0 * f1) * (f2 * f3)) * (f4 * f5);
        float re = prod * cphC, im = prod * sphC;

        // ---- precompute next step's phase from nxt (loaded 1 body ago) ----
        {
            float u = A[0]*nxt[0] + A[1]*nxt[1] + A[2]*nxt[2]
                    + A[3]*nxt[3] + A[4]*nxt[4] + A[5]*nxt[5];
            u = u - floorf(u);
            sphC = __builtin_amdgcn_sinf(u);
            cphC = __builtin_amdgcn_cosf(u);
        }

        // ---- apply U: 18 in-register gate stages (R4-verified chain) ----
        p1qv<32, 16, 48>(re, im, QARGS(0, 0));
        p1qv<8, 4, 12>(re, im, QARGS(0, 1));
        p1qv<2, 1, 3>(re, im, QARGS(0, 2));
        rngv<16, 8, 24>(re, im, RARGS(0, 0));
        rngv<4, 2, 6>(re, im, RARGS(0, 1));
        rngv<1, 32, 33>(re, im, RARGS(0, 2));
        rngv<2, 4, 6>(re, im, RARGS(0, 3));
        rngv<8, 16, 24>(re, im, RARGS(0, 4));
        rngv<32, 1, 33>(re, im, RARGS(0, 5));
        p1qv<32, 16, 48>(re, im, QARGS(1, 0));
        p1qv<8, 4, 12>(re, im, QARGS(1, 1));
        p1qv<2, 1, 3>(re, im, QARGS(1, 2));
        rngv<16, 8, 24>(re, im, RARGS(1, 0));
        rngv<4, 2, 6>(re, im, RARGS(1, 1));
        rngv<1, 32, 33>(re, im, RARGS(1, 2));
        rngv<2, 4, 6>(re, im, RARGS(1, 3));
        rngv<8, 16, 24>(re, im, RARGS(1, 4));
        rngv<32, 1, 33>(re, im, RARGS(1, 5));

        // ---- Z via WHT butterfly ----
        float P  = fmaf(re, re, im * im);
        float Wp = b6(P);                       // lane 32>>q holds Z_q
        float Z0 = rdl<32>(Wp), Z1 = rdl<16>(Wp), Z2 = rdl<8>(Wp);
        float Z3 = rdl<4>(Wp),  Z4 = rdl<2>(Wp),  Z5 = rdl<1>(Wp);

        // ---- partner states for all 6 masks (VALU-only) ----
        float g32r = exg<32>(re), g32i = exg<32>(im);
        float g16r = exg<16>(re), g16i = exg<16>(im);
        float g8r  = exg<8>(re),  g8i  = exg<8>(im);
        float g4r  = exg<4>(re),  g4i  = exg<4>(im);
        float g2r  = exg<2>(re),  g2i  = exg<2>(im);
        float g1r  = exg<1>(re),  g1i  = exg<1>(im);

        // ---- X via direct correlations (uniform results) ----
        float X0 = redsum64(fmaf(re, g32r, im * g32i));
        float X1 = redsum64(fmaf(re, g16r, im * g16i));
        float X2 = redsum64(fmaf(re, g8r,  im * g8i));
        float X3 = redsum64(fmaf(re, g4r,  im * g4i));
        float X4 = redsum64(fmaf(re, g2r,  im * g2i));
        float X5 = redsum64(fmaf(re, g1r,  im * g1i));

        // ---- h recurrence (cur[6..17] pre-scaled by 0.5/(2pi)) ----
        hh0 = cur[6]  * Z0 - cur[12] * X0;
        hh1 = cur[7]  * Z1 - cur[13] * X1;
        hh2 = cur[8]  * Z2 - cur[14] * X2;
        hh3 = cur[9]  * Z3 - cur[15] * X3;
        hh4 = cur[10] * Z4 - cur[16] * X4;
        hh5 = cur[11] * Z5 - cur[17] * X5;

        // ---- Y + stores, split by wave (disjoint output slots) ----
        float* o = outb + (size_t)t * 18;
        if (wave == 0) {
            if (lane == 0) {
                float2* o2 = (float2*)o;
                o2[0] = make_float2(Z0, Z1); o2[1] = make_float2(Z2, Z3);
                o2[2] = make_float2(Z4, Z5); o2[3] = make_float2(X0, X1);
                o2[4] = make_float2(X2, X3); o2[5] = make_float2(X4, X5);
            }
        } else if (wave == 1) {
            float Y0 = redsum64(xorf(fmaf(re, g32i, -(im * g32r)), sflip[0]));
            float Y1 = redsum64(xorf(fmaf(re, g16i, -(im * g16r)), sflip[1]));
            if (lane == 0) ((float2*)(o + 12))[0] = make_float2(Y0, Y1);
        } else if (wave == 2) {
            float Y2 = redsum64(xorf(fmaf(re, g8i, -(im * g8r)), sflip[2]));
            float Y3 = redsum64(xorf(fmaf(re, g4i, -(im * g4r)), sflip[3]));
            if (lane == 0) ((float2*)(o + 14))[0] = make_float2(Y2, Y3);
        } else {
            float Y4 = redsum64(xorf(fmaf(re, g2i, -(im * g2r)), sflip[4]));
            float Y5 = redsum64(xorf(fmaf(re, g1i, -(im * g1r)), sflip[5]));
            if (lane == 0) ((float2*)(o + 16))[0] = make_float2(Y4, Y5);
        }
    };

    for (int t = 0; t < 510; t += 3) {
        body(buf0, buf1, buf2, t);
        body(buf1, buf2, buf0, t + 1);
        body(buf2, buf0, buf1, t + 2);
    }
    body(buf0, buf1, buf2, 510);
    body(buf1, buf2, buf0, 511);
}

// ---------------------------------------------------------------------------
// post_kernel: finalize outputs in place over the raw Z/X/Y (R4-verified).
// ---------------------------------------------------------------------------
__global__ __launch_bounds__(256) void post_kernel(
    const float* __restrict__ sd, float* __restrict__ out)
{
    int gid = blockIdx.x * blockDim.x + threadIdx.x;
    if (gid >= BATCH * SEQ) return;
    const float* rec = sd + (size_t)gid * SDS;
    float* o = out + (size_t)gid * 18;

    float zxy[18];
    {
        const float2* o2 = (const float2*)o;
#pragma unroll
        for (int k = 0; k < 9; k++) {
            float2 v = o2[k];
            zxy[2 * k] = v.x; zxy[2 * k + 1] = v.y;
        }
    }
    float r[54];
    {
        const float2* r2 = (const float2*)rec;
#pragma unroll
        for (int k = 3; k < 27; k++) {       // floats 6..53 (hc,hs,Cc,term)
            float2 v = r2[k];
            r[2 * k] = v.x; r[2 * k + 1] = v.y;
        }
    }
    float res[18];
#pragma unroll
    for (int q = 0; q < 6; q++) {
        float Z = zxy[q], X = zxy[6 + q], Y = zxy[12 + q];
        float c = r[6 + q], s = r[12 + q];   // = 0.5/(2pi) * {cos, sin}
        float px = c * X + s * Z;
        float hq = c * Z - s * X;
        res[q]      = fmaf(r[18 + q], px, r[36 + q]);   // r18 = 4pi*Cc
        res[6 + q]  = fmaf(r[24 + q], Y,  r[42 + q]);   // unscaled
        res[12 + q] = fmaf(r[30 + q], hq, r[48 + q]);   // r30 = 4pi*Cc
    }
    float2* ow = (float2*)o;
#pragma unroll
    for (int k = 0; k < 9; k++) ow[k] = make_float2(res[2 * k], res[2 * k + 1]);
}

// ---------------------------------------------------------------------------
extern "C" void kernel_launch(void* const* d_in, const int* in_sizes, int n_in,
                              void* d_out, int out_size, void* d_ws, size_t ws_size,
                              hipStream_t stream) {
    const float* angles = (const float*)d_in[0];
    const float* Wx     = (const float*)d_in[1];
    const float* Wdt    = (const float*)d_in[2];
    const float* bdt    = (const float*)d_in[3];
    const float* pc     = (const float*)d_in[4];
    const float* qp     = (const float*)d_in[5];
    const float* cp     = (const float*)d_in[6];
    const float* D      = (const float*)d_in[7];
    const float* Wc     = (const float*)d_in[8];
    float* sd  = (float*)d_ws;                                // 28.3 MB
    float* out = (float*)d_out;

    prep_kernel<<<(BATCH * SEQ) / 256, 256, 0, stream>>>(angles, Wx, Wdt, bdt, D, Wc, sd);
    step_kernel<<<BATCH, 256, 0, stream>>>(sd, pc, qp, cp, out);
    post_kernel<<<(BATCH * SEQ) / 256, 256, 0, stream>>>(sd, out);
}